// Round 8
// baseline (301.290 us; speedup 1.0000x reference)
//
#include <hip/hip_runtime.h>

// Problem constants
#define SEQ  2048
#define NB   32
#define NS   512
#define MI   64   // M_IN
#define PO   64   // P_OUT
#define TB   64   // t-block
#define NTB  32   // SEQ/TB
#define CH   64   // i-chunk
#define NCH  8    // NS/CH
#define LDU  72   // u_b / Gb / Sw stride (ushort)
#define LDD  66   // buDiag stride (float): 2-way write aliasing, b64-aligned reads
#define SG_LDA 72 // sgemm LDS stride (ushort)

typedef __attribute__((ext_vector_type(8))) __bf16 bf16x8;
typedef __attribute__((ext_vector_type(4))) float  floatx4;

__device__ inline unsigned short f2bf(float f) {
    unsigned u = __builtin_bit_cast(unsigned, f);
    u += 0x7fff + ((u >> 16) & 1);           // RNE
    return (unsigned short)(u >> 16);
}

// ---------------------------------------------------------------------------
// Fused prep: [0,2048) u->bf16 | [2048,2560) BflatT | [2560,2624) q
// | [2624,2896) B/C/D -> bf16
// ---------------------------------------------------------------------------
__global__ void __launch_bounds__(256) prep_all_kernel(
    const float* __restrict__ u, const float* __restrict__ B,
    const float* __restrict__ C, const float* __restrict__ D,
    const float* __restrict__ a,
    unsigned short* __restrict__ ubf, unsigned short* __restrict__ BflatT,
    unsigned short* __restrict__ Bws, unsigned short* __restrict__ Cws,
    unsigned short* __restrict__ Dws, unsigned short* __restrict__ qT) {
    __shared__ float a_ext[1024];
    const int bx = blockIdx.x, tid = threadIdx.x;
    if (bx < 2048) {                       // ---- uconv
        const size_t base = ((size_t)bx * 256 + tid) * 8;
        float4 f0 = *(const float4*)(u + base);
        float4 f1 = *(const float4*)(u + base + 4);
        unsigned short tmp[8];
        tmp[0] = f2bf(f0.x); tmp[1] = f2bf(f0.y); tmp[2] = f2bf(f0.z); tmp[3] = f2bf(f0.w);
        tmp[4] = f2bf(f1.x); tmp[5] = f2bf(f1.y); tmp[6] = f2bf(f1.z); tmp[7] = f2bf(f1.w);
        *(uint4*)(ubf + base) = *(uint4*)&tmp[0];
    } else if (bx < 2560) {                // ---- BflatT[i][(j,m)] = B[i-j,m]
        const int i = bx - 2048;
        for (int r = 0; r < 2; ++r) {
            const int id = tid + r * 256;
            const int j = id >> 3, q8 = (id & 7) * 8;
            unsigned short tmp[8];
            if (i >= j) {
                const float4 f0 = *(const float4*)(B + (size_t)(i - j) * MI + q8);
                const float4 f1 = *(const float4*)(B + (size_t)(i - j) * MI + q8 + 4);
                tmp[0] = f2bf(f0.x); tmp[1] = f2bf(f0.y); tmp[2] = f2bf(f0.z); tmp[3] = f2bf(f0.w);
                tmp[4] = f2bf(f1.x); tmp[5] = f2bf(f1.y); tmp[6] = f2bf(f1.z); tmp[7] = f2bf(f1.w);
            } else {
#pragma unroll
                for (int z = 0; z < 8; ++z) tmp[z] = 0;
            }
            *(uint4*)(BflatT + (size_t)i * 4096 + j * 64 + q8) = *(uint4*)&tmp[0];
        }
    } else if (bx < 2624) {                // ---- q: qT[p][j]
        const int p = bx - 2560;
        for (int x = tid; x < 1024; x += 256) a_ext[x] = (x < NS) ? a[x] : 0.f;
        __syncthreads();
        const int j0 = tid, j1 = tid + 256;
        float acc0 = 0.f, acc1 = 0.f;
        const float4* crow = (const float4*)(C + (size_t)p * NS);
        for (int i4 = 0; i4 < NS / 4; ++i4) {
            const float4 cv = crow[i4];
            const int base = 511 - i4 * 4;
            acc0 += cv.x * a_ext[base + j0]     + cv.y * a_ext[base - 1 + j0] +
                    cv.z * a_ext[base - 2 + j0] + cv.w * a_ext[base - 3 + j0];
            acc1 += cv.x * a_ext[base + j1]     + cv.y * a_ext[base - 1 + j1] +
                    cv.z * a_ext[base - 2 + j1] + cv.w * a_ext[base - 3 + j1];
        }
        qT[(size_t)p * NS + j0] = f2bf(acc0);
        qT[(size_t)p * NS + j1] = f2bf(acc1);
    } else {                               // ---- B/C/D bf16 cvt
        const int idx = (bx - 2624) * 256 + tid;
        const int nB = NS * MI, nC = PO * NS, nD = PO * MI;
        if (idx < nB) Bws[idx] = f2bf(B[idx]);
        else if (idx < nB + nC) Cws[idx - nB] = f2bf(C[idx - nB]);
        else if (idx < nB + nC + nD) Dws[idx - nB - nC] = f2bf(D[idx - nB - nC]);
    }
}

// ---------------------------------------------------------------------------
// S-GEMM: S[(b,k), i] = sum_{(j,m)} BflatT[i][(j,m)] * u[b, k*64+63-j, m]
// Grid (8 i-blocks, 32 batches): 256 WGs -> one per CU.
// ---------------------------------------------------------------------------
__global__ void __launch_bounds__(256) sgemm_kernel(const unsigned short* __restrict__ ubf,
                                                    const unsigned short* __restrict__ BflatT,
                                                    float* __restrict__ Sbuf) {
    __shared__ unsigned short A_l[4 * 64 * SG_LDA];   // 36.9 KB
    __shared__ unsigned short U_l[4 * 32 * SG_LDA];   // 18.4 KB
    const int ib = blockIdx.x, b = blockIdx.y;
    const int tid = threadIdx.x, lane = tid & 63, w = tid >> 6;
    const int row16 = lane & 15, quad = lane >> 4;
    const int i0 = ib * 64;
    floatx4 acc[2];
#pragma unroll
    for (int ns = 0; ns < 2; ++ns) acc[ns] = (floatx4){0.f, 0.f, 0.f, 0.f};

    for (int jg = 0; jg < 16; ++jg) {
#pragma unroll
        for (int r = 0; r < 8; ++r) {
            const int id = tid + r * 256;        // 0..2047
            const int row = id >> 5;             // 0..63 (i row)
            const int jj = (id >> 3) & 3, q8 = (id & 7) * 8;
            const int j = jg * 4 + jj;
            *(uint4*)&A_l[(jj * 64 + row) * SG_LDA + q8] =
                *(const uint4*)(BflatT + (size_t)(i0 + row) * 4096 + j * 64 + q8);
        }
#pragma unroll
        for (int r = 0; r < 4; ++r) {
            const int id = tid + r * 256;        // 0..1023
            const int n = id >> 5;               // 0..31 (k-tile)
            const int jj = (id >> 3) & 3, q8 = (id & 7) * 8;
            const int j = jg * 4 + jj;
            *(uint4*)&U_l[(jj * 32 + n) * SG_LDA + q8] =
                *(const uint4*)(ubf + ((size_t)b * SEQ + n * 64 + 63 - j) * MI + q8);
        }
        __syncthreads();
#pragma unroll
        for (int jj = 0; jj < 4; ++jj) {
#pragma unroll
            for (int mk = 0; mk < 2; ++mk) {
                const bf16x8 av = *(const bf16x8*)
                    &A_l[(jj * 64 + w * 16 + row16) * SG_LDA + mk * 32 + quad * 8];
#pragma unroll
                for (int ns = 0; ns < 2; ++ns) {
                    const bf16x8 bv = *(const bf16x8*)
                        &U_l[(jj * 32 + ns * 16 + row16) * SG_LDA + mk * 32 + quad * 8];
                    acc[ns] = __builtin_amdgcn_mfma_f32_16x16x32_bf16(av, bv, acc[ns], 0, 0, 0);
                }
            }
        }
        __syncthreads();
    }
#pragma unroll
    for (int ns = 0; ns < 2; ++ns) {
        const int n = ns * 16 + row16;           // k-tile 0..31
        float* dst = Sbuf + ((size_t)b * NTB + n) * NS + i0 + w * 16 + quad * 4;
        *(floatx4*)dst = acc[ns];
    }
}

// ---------------------------------------------------------------------------
// Fused (1024 threads): blocks 0..31 = block-carry scan (per batch);
// block 32 = impulse response h (fixed-trip, register-cached taps).
// ---------------------------------------------------------------------------
__global__ void __launch_bounds__(1024) scan_himp_kernel(const float* __restrict__ Sbuf,
                                                         float* __restrict__ Rbuf,
                                                         const float* __restrict__ a,
                                                         float* __restrict__ hbuf) {
    __shared__ __align__(16) char smem[69632];
    const int tid = threadIdx.x;
    if (blockIdx.x < NB) {
        // ---------------- scan ----------------
        float* S_l = (float*)smem;                 // 64 KB
        float* Rc  = (float*)(smem + 65536);
        const int b = blockIdx.x;
        const float4* src = (const float4*)(Sbuf + (size_t)b * NTB * NS);
        for (int k = tid; k < NTB * NS / 4; k += 1024) ((float4*)S_l)[k] = src[k];
        if (tid < 128) ((float4*)Rc)[tid] = make_float4(0.f, 0.f, 0.f, 0.f);
        __syncthreads();
        int cur = 0;
        for (int k = 0; k < NTB; ++k) {
            if (tid < 128) {
                const int i0 = tid * 4;
                float4 r = *(const float4*)&Rc[cur * NS + i0];
                *(float4*)(Rbuf + ((size_t)b * NTB + k) * NS + i0) = r;
                float4 s = *(const float4*)&S_l[k * NS + i0];
                float4 rp = (i0 >= TB) ? *(const float4*)&Rc[cur * NS + i0 - TB]
                                       : make_float4(0.f, 0.f, 0.f, 0.f);
                float4 nv = make_float4(s.x + rp.x, s.y + rp.y, s.z + rp.z, s.w + rp.w);
                *(float4*)&Rc[(cur ^ 1) * NS + i0] = nv;
            }
            __syncthreads();
            cur ^= 1;
        }
    } else {
        // ---------------- himp ----------------
        float* a_l     = (float*)smem;                  // 640 floats (zero-pad)
        float* h_ext   = (float*)(smem + 2560);         // 512 zeros + h[0:2048]
        float* part    = (float*)(smem + 12800);        // 16 * 128
        float* rhs_ext = (float*)(smem + 20992);        // 128 zeros + 128
        const int kk = tid & 63, grp = tid >> 6;        // 16 groups of 64

        for (int x = tid; x < 640; x += 1024) a_l[x] = (x < NS) ? a[x] : 0.f;
        for (int x = tid; x < 512; x += 1024) h_ext[x] = 0.f;
        if (tid < 128) rhs_ext[tid] = 0.f;
        __syncthreads();

        float a0r[32], a1r[32];
#pragma unroll
        for (int i = 0; i < 32; ++i) a0r[i] = a_l[kk + grp * 32 + i];
#pragma unroll
        for (int i = 0; i < 32; ++i) a1r[i] = a_l[kk + 64 + grp * 32 + i];

        if (tid < 64) {
            if (tid == 0) h_ext[512] = 1.f;
            for (int t = 1; t < 64; ++t) {
                float pr = (tid < t) ? a_l[tid] * h_ext[512 + t - 1 - tid] : 0.f;
#pragma unroll
                for (int off = 32; off; off >>= 1) pr += __shfl_xor(pr, off);
                if (tid == 0) h_ext[512 + t] = -pr;
            }
        }
        __syncthreads();

        {   // doubling 64 -> 128
            const int t0 = 64;
            float acc0 = 0.f;
#pragma unroll
            for (int m = 0; m < 8; ++m) {
                const float4 hv = *(const float4*)&h_ext[512 + t0 - grp * 32 - 4 - 4 * m];
                acc0 += a0r[4 * m + 0] * hv.w + a0r[4 * m + 1] * hv.z +
                        a0r[4 * m + 2] * hv.y + a0r[4 * m + 3] * hv.x;
            }
            part[grp * 128 + kk] = acc0;
            __syncthreads();
            if (tid < 64) {
                float r = 0.f;
#pragma unroll
                for (int g = 0; g < 16; ++g) r += part[g * 128 + tid];
                rhs_ext[128 + tid] = -r;
            }
            __syncthreads();
            if (tid < 64) {
                float s0 = 0.f, s1 = 0.f, s2 = 0.f, s3 = 0.f;
#pragma unroll
                for (int j = 0; j < 64; j += 4) {
                    const float4 h4 = *(const float4*)&h_ext[512 + j];
                    s0 += h4.x * rhs_ext[128 + tid - j];
                    s1 += h4.y * rhs_ext[128 + tid - j - 1];
                    s2 += h4.z * rhs_ext[128 + tid - j - 2];
                    s3 += h4.w * rhs_ext[128 + tid - j - 3];
                }
                h_ext[512 + t0 + tid] = s0 + s1 + s2 + s3;
            }
            __syncthreads();
        }

        for (int t0 = 128; t0 < SEQ; t0 += 128) {
            float acc0 = 0.f, acc1 = 0.f;
#pragma unroll
            for (int m = 0; m < 8; ++m) {
                const float4 hv = *(const float4*)&h_ext[512 + t0 - grp * 32 - 4 - 4 * m];
                acc0 += a0r[4 * m + 0] * hv.w + a0r[4 * m + 1] * hv.z +
                        a0r[4 * m + 2] * hv.y + a0r[4 * m + 3] * hv.x;
                acc1 += a1r[4 * m + 0] * hv.w + a1r[4 * m + 1] * hv.z +
                        a1r[4 * m + 2] * hv.y + a1r[4 * m + 3] * hv.x;
            }
            part[grp * 128 + kk]      = acc0;
            part[grp * 128 + kk + 64] = acc1;
            __syncthreads();
            if (tid < 128) {
                float r = 0.f;
#pragma unroll
                for (int g = 0; g < 16; ++g) r += part[g * 128 + tid];
                rhs_ext[128 + tid] = -r;
            }
            __syncthreads();
            if (tid < 128) {
                float s0 = 0.f, s1 = 0.f, s2 = 0.f, s3 = 0.f;
#pragma unroll
                for (int j = 0; j < 128; j += 4) {
                    const float4 h4 = *(const float4*)&h_ext[512 + j];
                    s0 += h4.x * rhs_ext[128 + tid - j];
                    s1 += h4.y * rhs_ext[128 + tid - j - 1];
                    s2 += h4.z * rhs_ext[128 + tid - j - 2];
                    s3 += h4.w * rhs_ext[128 + tid - j - 3];
                }
                h_ext[512 + t0 + tid] = s0 + s1 + s2 + s3;
            }
            __syncthreads();
        }
        for (int i = tid; i < SEQ; i += 1024) hbuf[i] = h_ext[512 + i];
    }
}

// ---------------------------------------------------------------------------
// ytile (MFMA): per (t-block, batch). Phase A scatters Bu to DIAG-MAJOR
// buDiag[d][t] (d = (i-t)&63); walk = ONE WAVE, register-resident chains:
// lane d owns row d = two complete diagonals contiguous in t. G written bf16
// -> phase B MFMA reads directly. y = C*G + D*u; emit f.
// ---------------------------------------------------------------------------
__global__ void __launch_bounds__(256, 4) ytile_kernel(
    const unsigned short* __restrict__ ubf, const unsigned short* __restrict__ Bws,
    const unsigned short* __restrict__ Cws, const unsigned short* __restrict__ Dws,
    const float* __restrict__ Rbuf, float* __restrict__ fbuf, float* __restrict__ y) {
    __shared__ unsigned short u_b[TB * LDU];   // 9.2 KB
    __shared__ float buDiag[TB * LDD];         // 16.9 KB
    __shared__ unsigned short Gb[TB * LDU];    // 9.2 KB
    __shared__ float colBuf[2][TB];

    const int blk = blockIdx.x, b = blockIdx.y;
    const int t0 = blk * TB;
    const int tid = threadIdx.x;
    const int lane = tid & 63, w = tid >> 6;
    const int row16 = lane & 15, quad = lane >> 4;
    const size_t rbase = ((size_t)b * NTB + blk) * NS;

    // stage u tile (bf16, pre-converted)
#pragma unroll
    for (int r = 0; r < 2; ++r) {
        const int id = tid + r * 256;
        const int t = id >> 3, q8 = (id & 7) * 8;
        *(uint4*)&u_b[t * LDU + q8] =
            *(const uint4*)(ubf + ((size_t)b * SEQ + t0 + t) * MI + q8);
    }
    if (tid < TB) colBuf[0][tid] = 0.f;

    floatx4 accY[4];
#pragma unroll
    for (int nt = 0; nt < 4; ++nt) accY[nt] = (floatx4){0.f, 0.f, 0.f, 0.f};
    __syncthreads();

    // preload u B-operand frags once
    bf16x8 ufr0[4], ufr1[4];
#pragma unroll
    for (int nt = 0; nt < 4; ++nt) {
        const int t = nt * 16 + row16;
        ufr0[nt] = *(const bf16x8*)&u_b[t * LDU + quad * 8];
        ufr1[nt] = *(const bf16x8*)&u_b[t * LDU + 32 + quad * 8];
    }

    int cur = 0;
    for (int ch = 0; ch < NCH; ++ch) {
        const bf16x8 bf0 = *(const bf16x8*)(Bws + (size_t)(ch * CH + w * 16 + row16) * MI + quad * 8);
        const bf16x8 bf1 = *(const bf16x8*)(Bws + (size_t)(ch * CH + w * 16 + row16) * MI + 32 + quad * 8);
        const bf16x8 cf0 = *(const bf16x8*)(Cws + (size_t)(w * 16 + row16) * NS + ch * CH + quad * 8);
        const bf16x8 cf1 = *(const bf16x8*)(Cws + (size_t)(w * 16 + row16) * NS + ch * CH + 32 + quad * 8);

        // phase A: Bu chunk -> buDiag (diag-major scatter)
#pragma unroll
        for (int nt = 0; nt < 4; ++nt) {
            floatx4 dacc = {0.f, 0.f, 0.f, 0.f};
            dacc = __builtin_amdgcn_mfma_f32_16x16x32_bf16(bf0, ufr0[nt], dacc, 0, 0, 0);
            dacc = __builtin_amdgcn_mfma_f32_16x16x32_bf16(bf1, ufr1[nt], dacc, 0, 0, 0);
            const int t = nt * 16 + row16;
            const int ibase = w * 16 + quad * 4;
#pragma unroll
            for (int r = 0; r < 4; ++r) {
                const int dd = (ibase + r - t) & 63;
                buDiag[dd * LDD + t] = dacc[r];
            }
        }
        __syncthreads();

        // ---- walk: wave 0 only; lane d owns row d (two chains, in-register)
        const int nxt = cur ^ 1;
        if (tid < 64) {
            const int d = tid;
            const int gi = ch * CH + d;
            float run = (gi >= 1) ? Rbuf[rbase + gi - 1] : 0.f;      // chain A seed
            const float carryB = (ch > 0) ? colBuf[cur][d] : 0.f;    // chain B seed
            const int tsplit = 63 - d;
            float exitVal = 0.f;
            // half 1: t = 0..31
            float v[32];
#pragma unroll
            for (int k = 0; k < 16; ++k) {
                const float2 tv = *(const float2*)&buDiag[d * LDD + 2 * k];
                v[2 * k] = tv.x; v[2 * k + 1] = tv.y;
            }
#pragma unroll
            for (int t = 0; t < 32; ++t) {
                run += v[t];
                Gb[t * LDU + ((d + t) & 63)] = f2bf(run);
                const bool sp = (t == tsplit);
                exitVal = sp ? run : exitVal;
                run = sp ? carryB : run;
            }
            // half 2: t = 32..63
#pragma unroll
            for (int k = 0; k < 16; ++k) {
                const float2 tv = *(const float2*)&buDiag[d * LDD + 32 + 2 * k];
                v[2 * k] = tv.x; v[2 * k + 1] = tv.y;
            }
#pragma unroll
            for (int t = 32; t < 64; ++t) {
                run += v[t - 32];
                Gb[t * LDU + ((d + t) & 63)] = f2bf(run);
                const bool sp = (t == tsplit);
                exitVal = sp ? run : exitVal;
                run = sp ? carryB : run;
            }
            // chain A exit (at t = tsplit, i reached chunk top)
            if (ch == NCH - 1) fbuf[(size_t)b * SEQ + t0 + tsplit] = exitVal;
            else colBuf[nxt][d] = exitVal;
        }
        __syncthreads();

        // phase B: accY += C[:,chunk] * G[chunk]  (bf16 direct)
#pragma unroll
        for (int nt = 0; nt < 4; ++nt) {
            const int t = nt * 16 + row16;
            bf16x8 g0 = *(const bf16x8*)&Gb[t * LDU + quad * 8];
            bf16x8 g1 = *(const bf16x8*)&Gb[t * LDU + 32 + quad * 8];
            accY[nt] = __builtin_amdgcn_mfma_f32_16x16x32_bf16(cf0, g0, accY[nt], 0, 0, 0);
            accY[nt] = __builtin_amdgcn_mfma_f32_16x16x32_bf16(cf1, g1, accY[nt], 0, 0, 0);
        }
        __syncthreads();
        cur = nxt;
    }

    // epilogue: += D*u, store y
    const bf16x8 df0 = *(const bf16x8*)(Dws + (size_t)(w * 16 + row16) * MI + quad * 8);
    const bf16x8 df1 = *(const bf16x8*)(Dws + (size_t)(w * 16 + row16) * MI + 32 + quad * 8);
#pragma unroll
    for (int nt = 0; nt < 4; ++nt) {
        const int t = nt * 16 + row16;
        accY[nt] = __builtin_amdgcn_mfma_f32_16x16x32_bf16(df0, ufr0[nt], accY[nt], 0, 0, 0);
        accY[nt] = __builtin_amdgcn_mfma_f32_16x16x32_bf16(df1, ufr1[nt], accY[nt], 0, 0, 0);
        const int p0 = w * 16 + quad * 4;
        *(floatx4*)(y + ((size_t)b * SEQ + t0 + t) * PO + p0) = accY[nt];
    }
}

// ---------------------------------------------------------------------------
// s[b][t] = sum_{j=0..t} h[j] f[b][t-j]
// ---------------------------------------------------------------------------
__global__ void __launch_bounds__(256) sconv_kernel(const float* __restrict__ fbuf,
                                                    const float* __restrict__ hbuf,
                                                    float* __restrict__ sbuf) {
    __shared__ float f_l[SEQ];
    __shared__ float h_lc[SEQ + 8];
    __shared__ float part[4][TB];
    const int blk = blockIdx.x, b = blockIdx.y, tid = threadIdx.x;
    const int t0 = blk * TB;
    const int len = t0 + TB;
    {
        const float4* fs = (const float4*)(fbuf + (size_t)b * SEQ);
        const float4* hs = (const float4*)hbuf;
        for (int i = tid; i < len / 4; i += 256) {
            ((float4*)f_l)[i] = fs[i];
            ((float4*)h_lc)[i] = hs[i];
        }
    }
    __syncthreads();
    const int dt = tid & 63, grp = tid >> 6;
    const int t = t0 + dt;
    float acc = 0.f;
    for (int j4 = grp * 4; j4 <= t; j4 += 16) {
        const float4 hv = *(const float4*)&h_lc[j4];
        if (j4 + 0 <= t) acc += hv.x * f_l[t - j4 - 0];
        if (j4 + 1 <= t) acc += hv.y * f_l[t - j4 - 1];
        if (j4 + 2 <= t) acc += hv.z * f_l[t - j4 - 2];
        if (j4 + 3 <= t) acc += hv.w * f_l[t - j4 - 3];
    }
    part[grp][dt] = acc;
    __syncthreads();
    if (tid < TB) {
        sbuf[(size_t)b * SEQ + t0 + tid] =
            part[0][tid] + part[1][tid] + part[2][tid] + part[3][tid];
    }
}

// ---------------------------------------------------------------------------
// corr (MFMA, direct global q-frags, double-buffered Sw, 1 barrier/chunk):
// y[b,t,p] -= sum_j qT[p][j] * s[b, t-1-j]
// ---------------------------------------------------------------------------
__global__ void __launch_bounds__(256) corr_kernel(
    const float* __restrict__ sbuf, const unsigned short* __restrict__ qT,
    float* __restrict__ y) {
    __shared__ float s_l[NS + TB];
    __shared__ unsigned short Sw[2][TB * LDU];
    const int blk = blockIdx.x, b = blockIdx.y, tid = threadIdx.x;
    const int t0 = blk * TB;
    const int lane = tid & 63, w = tid >> 6;
    const int row16 = lane & 15, quad = lane >> 4;
    for (int idx = tid; idx < NS + TB; idx += 256) {
        const int t = t0 - NS + idx;
        s_l[idx] = (t >= 0) ? sbuf[(size_t)b * SEQ + t] : 0.f;
    }
    floatx4 acc[4];
#pragma unroll
    for (int nt = 0; nt < 4; ++nt) acc[nt] = (floatx4){0.f, 0.f, 0.f, 0.f};
    __syncthreads();

    for (int ch = 0; ch < NCH; ++ch) {
        const int buf = ch & 1;
        const bf16x8 qf0 = *(const bf16x8*)(qT + (size_t)(w * 16 + row16) * NS + ch * CH + quad * 8);
        const bf16x8 qf1 = *(const bf16x8*)(qT + (size_t)(w * 16 + row16) * NS + ch * CH + 32 + quad * 8);
        {
            const int r = tid >> 2, c0 = (tid & 3) * 16;
            unsigned short tmp[16];
            const int base = 511 + r - ch * CH - c0;
#pragma unroll
            for (int jj = 0; jj < 16; ++jj) tmp[jj] = f2bf(s_l[base - jj]);
            *(uint4*)&Sw[buf][r * LDU + c0]     = *(uint4*)&tmp[0];
            *(uint4*)&Sw[buf][r * LDU + c0 + 8] = *(uint4*)&tmp[8];
        }
        __syncthreads();
#pragma unroll
        for (int nt = 0; nt < 4; ++nt) {
            const int t = nt * 16 + row16;
            bf16x8 s0 = *(const bf16x8*)&Sw[buf][t * LDU + quad * 8];
            bf16x8 s1 = *(const bf16x8*)&Sw[buf][t * LDU + 32 + quad * 8];
            acc[nt] = __builtin_amdgcn_mfma_f32_16x16x32_bf16(qf0, s0, acc[nt], 0, 0, 0);
            acc[nt] = __builtin_amdgcn_mfma_f32_16x16x32_bf16(qf1, s1, acc[nt], 0, 0, 0);
        }
    }
#pragma unroll
    for (int nt = 0; nt < 4; ++nt) {
        const int t = nt * 16 + row16;
        const int p0 = w * 16 + quad * 4;
        float* yp = y + ((size_t)b * SEQ + t0 + t) * PO + p0;
        floatx4 old = *(const floatx4*)yp;
        *(floatx4*)yp = old - acc[nt];
    }
}

// ---------------------------------------------------------------------------
extern "C" void kernel_launch(void* const* d_in, const int* in_sizes, int n_in,
                              void* d_out, int out_size, void* d_ws,
                              size_t ws_size, hipStream_t stream) {
    const float* u  = (const float*)d_in[0];
    const float* a  = (const float*)d_in[1];
    const float* B  = (const float*)d_in[2];
    const float* Cm = (const float*)d_in[3];
    const float* Dm = (const float*)d_in[4];
    float* y = (float*)d_out;

    char* ws = (char*)d_ws;
    unsigned short* Bws = (unsigned short*)ws;                  ws += NS * MI * 2;
    unsigned short* Cws = (unsigned short*)ws;                  ws += PO * NS * 2;
    unsigned short* Dws = (unsigned short*)ws;                  ws += PO * MI * 2;
    unsigned short* qTw = (unsigned short*)ws;                  ws += PO * NS * 2;
    unsigned short* ubf = (unsigned short*)ws;                  ws += (size_t)NB * SEQ * MI * 2;
    unsigned short* Bft = (unsigned short*)ws;                  ws += (size_t)NS * 4096 * 2;
    float* Sbuf = (float*)ws;                                   ws += (size_t)NB * NTB * NS * 4;
    float* Rbuf = (float*)ws;                                   ws += (size_t)NB * NTB * NS * 4;
    float* fbuf = (float*)ws;                                   ws += (size_t)NB * SEQ * 4;
    float* sbuf = (float*)ws;                                   ws += (size_t)NB * SEQ * 4;
    float* hbuf = (float*)ws;                                   // 2048 floats (~17.5 MB total)

    prep_all_kernel<<<dim3(2896), dim3(256), 0, stream>>>(
        u, B, Cm, Dm, a, ubf, Bft, Bws, Cws, Dws, qTw);
    sgemm_kernel<<<dim3(8, 32), dim3(256), 0, stream>>>(ubf, Bft, Sbuf);
    scan_himp_kernel<<<dim3(NB + 1), dim3(1024), 0, stream>>>(Sbuf, Rbuf, a, hbuf);
    ytile_kernel<<<dim3(NTB, NB), dim3(256), 0, stream>>>(
        ubf, Bws, Cws, Dws, Rbuf, fbuf, y);
    sconv_kernel<<<dim3(NTB, NB), dim3(256), 0, stream>>>(fbuf, hbuf, sbuf);
    corr_kernel<<<dim3(NTB, NB), dim3(256), 0, stream>>>(sbuf, qTw, y);
}

// Round 9
// 251.512 us; speedup vs baseline: 1.1979x; 1.1979x over previous
//
#include <hip/hip_runtime.h>

// Problem constants
#define SEQ  2048
#define NB   32
#define NS   512
#define MI   64   // M_IN
#define PO   64   // P_OUT
#define TB   64   // t-block
#define NTB  32   // SEQ/TB
#define CH   64   // i-chunk
#define NCH  8    // NS/CH
#define LDU  72   // u_b / Gb / Sw stride (ushort)
#define LDD  66   // buDiag stride (float): 2-way aliasing only (free)
#define SG_LDA 72 // sgemm LDS stride (ushort)

typedef __attribute__((ext_vector_type(8))) __bf16 bf16x8;
typedef __attribute__((ext_vector_type(4))) float  floatx4;

__device__ inline unsigned short f2bf(float f) {
    unsigned u = __builtin_bit_cast(unsigned, f);
    u += 0x7fff + ((u >> 16) & 1);           // RNE
    return (unsigned short)(u >> 16);
}

// ---------------------------------------------------------------------------
// Fused prep: [0,2048) u->bf16 | [2048,2560) BflatT | [2560,2624) q
// | [2624,2896) B/C/D -> bf16
// ---------------------------------------------------------------------------
__global__ void __launch_bounds__(256) prep_all_kernel(
    const float* __restrict__ u, const float* __restrict__ B,
    const float* __restrict__ C, const float* __restrict__ D,
    const float* __restrict__ a,
    unsigned short* __restrict__ ubf, unsigned short* __restrict__ BflatT,
    unsigned short* __restrict__ Bws, unsigned short* __restrict__ Cws,
    unsigned short* __restrict__ Dws, unsigned short* __restrict__ qT) {
    __shared__ float a_ext[1024];
    const int bx = blockIdx.x, tid = threadIdx.x;
    if (bx < 2048) {                       // ---- uconv
        const size_t base = ((size_t)bx * 256 + tid) * 8;
        float4 f0 = *(const float4*)(u + base);
        float4 f1 = *(const float4*)(u + base + 4);
        unsigned short tmp[8];
        tmp[0] = f2bf(f0.x); tmp[1] = f2bf(f0.y); tmp[2] = f2bf(f0.z); tmp[3] = f2bf(f0.w);
        tmp[4] = f2bf(f1.x); tmp[5] = f2bf(f1.y); tmp[6] = f2bf(f1.z); tmp[7] = f2bf(f1.w);
        *(uint4*)(ubf + base) = *(uint4*)&tmp[0];
    } else if (bx < 2560) {                // ---- BflatT[i][(j,m)] = B[i-j,m]
        const int i = bx - 2048;
        for (int r = 0; r < 2; ++r) {
            const int id = tid + r * 256;
            const int j = id >> 3, q8 = (id & 7) * 8;
            unsigned short tmp[8];
            if (i >= j) {
                const float4 f0 = *(const float4*)(B + (size_t)(i - j) * MI + q8);
                const float4 f1 = *(const float4*)(B + (size_t)(i - j) * MI + q8 + 4);
                tmp[0] = f2bf(f0.x); tmp[1] = f2bf(f0.y); tmp[2] = f2bf(f0.z); tmp[3] = f2bf(f0.w);
                tmp[4] = f2bf(f1.x); tmp[5] = f2bf(f1.y); tmp[6] = f2bf(f1.z); tmp[7] = f2bf(f1.w);
            } else {
#pragma unroll
                for (int z = 0; z < 8; ++z) tmp[z] = 0;
            }
            *(uint4*)(BflatT + (size_t)i * 4096 + j * 64 + q8) = *(uint4*)&tmp[0];
        }
    } else if (bx < 2624) {                // ---- q: qT[p][j]
        const int p = bx - 2560;
        for (int x = tid; x < 1024; x += 256) a_ext[x] = (x < NS) ? a[x] : 0.f;
        __syncthreads();
        const int j0 = tid, j1 = tid + 256;
        float acc0 = 0.f, acc1 = 0.f;
        const float4* crow = (const float4*)(C + (size_t)p * NS);
        for (int i4 = 0; i4 < NS / 4; ++i4) {
            const float4 cv = crow[i4];
            const int base = 511 - i4 * 4;
            acc0 += cv.x * a_ext[base + j0]     + cv.y * a_ext[base - 1 + j0] +
                    cv.z * a_ext[base - 2 + j0] + cv.w * a_ext[base - 3 + j0];
            acc1 += cv.x * a_ext[base + j1]     + cv.y * a_ext[base - 1 + j1] +
                    cv.z * a_ext[base - 2 + j1] + cv.w * a_ext[base - 3 + j1];
        }
        qT[(size_t)p * NS + j0] = f2bf(acc0);
        qT[(size_t)p * NS + j1] = f2bf(acc1);
    } else {                               // ---- B/C/D bf16 cvt
        const int idx = (bx - 2624) * 256 + tid;
        const int nB = NS * MI, nC = PO * NS, nD = PO * MI;
        if (idx < nB) Bws[idx] = f2bf(B[idx]);
        else if (idx < nB + nC) Cws[idx - nB] = f2bf(C[idx - nB]);
        else if (idx < nB + nC + nD) Dws[idx - nB - nC] = f2bf(D[idx - nB - nC]);
    }
}

// ---------------------------------------------------------------------------
// S-GEMM: S[(b,k), i] = sum_{(j,m)} BflatT[i][(j,m)] * u[b, k*64+63-j, m]
// ---------------------------------------------------------------------------
__global__ void __launch_bounds__(256) sgemm_kernel(const unsigned short* __restrict__ ubf,
                                                    const unsigned short* __restrict__ BflatT,
                                                    float* __restrict__ Sbuf) {
    __shared__ unsigned short A_l[4 * 64 * SG_LDA];   // 36.9 KB
    __shared__ unsigned short U_l[4 * 32 * SG_LDA];   // 18.4 KB
    const int ib = blockIdx.x, b = blockIdx.y;
    const int tid = threadIdx.x, lane = tid & 63, w = tid >> 6;
    const int row16 = lane & 15, quad = lane >> 4;
    const int i0 = ib * 64;
    floatx4 acc[2];
#pragma unroll
    for (int ns = 0; ns < 2; ++ns) acc[ns] = (floatx4){0.f, 0.f, 0.f, 0.f};

    for (int jg = 0; jg < 16; ++jg) {
#pragma unroll
        for (int r = 0; r < 8; ++r) {
            const int id = tid + r * 256;
            const int row = id >> 5;
            const int jj = (id >> 3) & 3, q8 = (id & 7) * 8;
            const int j = jg * 4 + jj;
            *(uint4*)&A_l[(jj * 64 + row) * SG_LDA + q8] =
                *(const uint4*)(BflatT + (size_t)(i0 + row) * 4096 + j * 64 + q8);
        }
#pragma unroll
        for (int r = 0; r < 4; ++r) {
            const int id = tid + r * 256;
            const int n = id >> 5;
            const int jj = (id >> 3) & 3, q8 = (id & 7) * 8;
            const int j = jg * 4 + jj;
            *(uint4*)&U_l[(jj * 32 + n) * SG_LDA + q8] =
                *(const uint4*)(ubf + ((size_t)b * SEQ + n * 64 + 63 - j) * MI + q8);
        }
        __syncthreads();
#pragma unroll
        for (int jj = 0; jj < 4; ++jj) {
#pragma unroll
            for (int mk = 0; mk < 2; ++mk) {
                const bf16x8 av = *(const bf16x8*)
                    &A_l[(jj * 64 + w * 16 + row16) * SG_LDA + mk * 32 + quad * 8];
#pragma unroll
                for (int ns = 0; ns < 2; ++ns) {
                    const bf16x8 bv = *(const bf16x8*)
                        &U_l[(jj * 32 + ns * 16 + row16) * SG_LDA + mk * 32 + quad * 8];
                    acc[ns] = __builtin_amdgcn_mfma_f32_16x16x32_bf16(av, bv, acc[ns], 0, 0, 0);
                }
            }
        }
        __syncthreads();
    }
#pragma unroll
    for (int ns = 0; ns < 2; ++ns) {
        const int n = ns * 16 + row16;
        float* dst = Sbuf + ((size_t)b * NTB + n) * NS + i0 + w * 16 + quad * 4;
        *(floatx4*)dst = acc[ns];
    }
}

// ---------------------------------------------------------------------------
// Fused (1024 threads): blocks 0..31 = scan via CLOSED FORM (no barriers):
//   R_k[i] = sum_{m=0..7, m<=k-1, i>=64m} S_{k-1-m}[i-64m]
// block 32 = impulse response h (fixed-trip, register-cached taps).
// ---------------------------------------------------------------------------
__global__ void __launch_bounds__(1024) scan_himp_kernel(const float* __restrict__ Sbuf,
                                                         float* __restrict__ Rbuf,
                                                         const float* __restrict__ a,
                                                         float* __restrict__ hbuf) {
    __shared__ __align__(16) char smem[24576];
    const int tid = threadIdx.x;
    if (blockIdx.x < NB) {
        // ---------------- scan (closed form, fully parallel) ----------------
        const int b = blockIdx.x;
        const float4* S4 = (const float4*)(Sbuf + (size_t)b * NTB * NS);
        float4* R4 = (float4*)(Rbuf + (size_t)b * NTB * NS);
        for (int o = tid; o < NTB * NS / 4; o += 1024) {
            const int k = o >> 7;            // row (NS/4 = 128 float4 per row)
            const int i4 = o & 127;
            float4 acc = make_float4(0.f, 0.f, 0.f, 0.f);
#pragma unroll
            for (int m = 0; m < 8; ++m) {
                if (m <= k - 1 && i4 >= 16 * m) {
                    const float4 s = S4[(k - 1 - m) * 128 + i4 - 16 * m];
                    acc.x += s.x; acc.y += s.y; acc.z += s.z; acc.w += s.w;
                }
            }
            R4[o] = acc;
        }
    } else {
        // ---------------- himp ----------------
        float* a_l     = (float*)smem;                  // 640 floats (zero-pad)
        float* h_ext   = (float*)(smem + 2560);         // 512 zeros + h[0:2048]
        float* part    = (float*)(smem + 12800);        // 16 * 128
        float* rhs_ext = (float*)(smem + 20992);        // 128 zeros + 128
        const int kk = tid & 63, grp = tid >> 6;        // 16 groups of 64

        for (int x = tid; x < 640; x += 1024) a_l[x] = (x < NS) ? a[x] : 0.f;
        for (int x = tid; x < 512; x += 1024) h_ext[x] = 0.f;
        if (tid < 128) rhs_ext[tid] = 0.f;
        __syncthreads();

        float a0r[32], a1r[32];
#pragma unroll
        for (int i = 0; i < 32; ++i) a0r[i] = a_l[kk + grp * 32 + i];
#pragma unroll
        for (int i = 0; i < 32; ++i) a1r[i] = a_l[kk + 64 + grp * 32 + i];

        if (tid < 64) {
            if (tid == 0) h_ext[512] = 1.f;
            for (int t = 1; t < 64; ++t) {
                float pr = (tid < t) ? a_l[tid] * h_ext[512 + t - 1 - tid] : 0.f;
#pragma unroll
                for (int off = 32; off; off >>= 1) pr += __shfl_xor(pr, off);
                if (tid == 0) h_ext[512 + t] = -pr;
            }
        }
        __syncthreads();

        {   // doubling 64 -> 128
            const int t0 = 64;
            float acc0 = 0.f;
#pragma unroll
            for (int m = 0; m < 8; ++m) {
                const float4 hv = *(const float4*)&h_ext[512 + t0 - grp * 32 - 4 - 4 * m];
                acc0 += a0r[4 * m + 0] * hv.w + a0r[4 * m + 1] * hv.z +
                        a0r[4 * m + 2] * hv.y + a0r[4 * m + 3] * hv.x;
            }
            part[grp * 128 + kk] = acc0;
            __syncthreads();
            if (tid < 64) {
                float r = 0.f;
#pragma unroll
                for (int g = 0; g < 16; ++g) r += part[g * 128 + tid];
                rhs_ext[128 + tid] = -r;
            }
            __syncthreads();
            if (tid < 64) {
                float s0 = 0.f, s1 = 0.f, s2 = 0.f, s3 = 0.f;
#pragma unroll
                for (int j = 0; j < 64; j += 4) {
                    const float4 h4 = *(const float4*)&h_ext[512 + j];
                    s0 += h4.x * rhs_ext[128 + tid - j];
                    s1 += h4.y * rhs_ext[128 + tid - j - 1];
                    s2 += h4.z * rhs_ext[128 + tid - j - 2];
                    s3 += h4.w * rhs_ext[128 + tid - j - 3];
                }
                h_ext[512 + t0 + tid] = s0 + s1 + s2 + s3;
            }
            __syncthreads();
        }

        for (int t0 = 128; t0 < SEQ; t0 += 128) {
            float acc0 = 0.f, acc1 = 0.f;
#pragma unroll
            for (int m = 0; m < 8; ++m) {
                const float4 hv = *(const float4*)&h_ext[512 + t0 - grp * 32 - 4 - 4 * m];
                acc0 += a0r[4 * m + 0] * hv.w + a0r[4 * m + 1] * hv.z +
                        a0r[4 * m + 2] * hv.y + a0r[4 * m + 3] * hv.x;
                acc1 += a1r[4 * m + 0] * hv.w + a1r[4 * m + 1] * hv.z +
                        a1r[4 * m + 2] * hv.y + a1r[4 * m + 3] * hv.x;
            }
            part[grp * 128 + kk]      = acc0;
            part[grp * 128 + kk + 64] = acc1;
            __syncthreads();
            if (tid < 128) {
                float r = 0.f;
#pragma unroll
                for (int g = 0; g < 16; ++g) r += part[g * 128 + tid];
                rhs_ext[128 + tid] = -r;
            }
            __syncthreads();
            if (tid < 128) {
                float s0 = 0.f, s1 = 0.f, s2 = 0.f, s3 = 0.f;
#pragma unroll
                for (int j = 0; j < 128; j += 4) {
                    const float4 h4 = *(const float4*)&h_ext[512 + j];
                    s0 += h4.x * rhs_ext[128 + tid - j];
                    s1 += h4.y * rhs_ext[128 + tid - j - 1];
                    s2 += h4.z * rhs_ext[128 + tid - j - 2];
                    s3 += h4.w * rhs_ext[128 + tid - j - 3];
                }
                h_ext[512 + t0 + tid] = s0 + s1 + s2 + s3;
            }
            __syncthreads();
        }
        for (int i = tid; i < SEQ; i += 1024) hbuf[i] = h_ext[512 + i];
    }
}

// ---------------------------------------------------------------------------
// ytile (MFMA): per (t-block, batch). Phase A scatters Bu to diag-major
// buDiag[d][t]; walk = wave 0, lane d owns row d (two chains), float2 streamed
// reads (NO staging array -> no spill), chain in registers; G written bf16;
// phase B/epilogue MFMA; emit f.
// ---------------------------------------------------------------------------
__global__ void __launch_bounds__(256) ytile_kernel(
    const unsigned short* __restrict__ ubf, const unsigned short* __restrict__ Bws,
    const unsigned short* __restrict__ Cws, const unsigned short* __restrict__ Dws,
    const float* __restrict__ Rbuf, float* __restrict__ fbuf, float* __restrict__ y) {
    __shared__ unsigned short u_b[TB * LDU];   // 9.2 KB
    __shared__ float buDiag[TB * LDD];         // 16.9 KB
    __shared__ unsigned short Gb[TB * LDU];    // 9.2 KB
    __shared__ float colBuf[2][TB];

    const int blk = blockIdx.x, b = blockIdx.y;
    const int t0 = blk * TB;
    const int tid = threadIdx.x;
    const int lane = tid & 63, w = tid >> 6;
    const int row16 = lane & 15, quad = lane >> 4;
    const size_t rbase = ((size_t)b * NTB + blk) * NS;

    // stage u tile (bf16, pre-converted)
#pragma unroll
    for (int r = 0; r < 2; ++r) {
        const int id = tid + r * 256;
        const int t = id >> 3, q8 = (id & 7) * 8;
        *(uint4*)&u_b[t * LDU + q8] =
            *(const uint4*)(ubf + ((size_t)b * SEQ + t0 + t) * MI + q8);
    }
    if (tid < TB) colBuf[0][tid] = 0.f;

    floatx4 accY[4];
#pragma unroll
    for (int nt = 0; nt < 4; ++nt) accY[nt] = (floatx4){0.f, 0.f, 0.f, 0.f};
    __syncthreads();

    // preload u B-operand frags once
    bf16x8 ufr0[4], ufr1[4];
#pragma unroll
    for (int nt = 0; nt < 4; ++nt) {
        const int t = nt * 16 + row16;
        ufr0[nt] = *(const bf16x8*)&u_b[t * LDU + quad * 8];
        ufr1[nt] = *(const bf16x8*)&u_b[t * LDU + 32 + quad * 8];
    }

    int cur = 0;
    for (int ch = 0; ch < NCH; ++ch) {
        const bf16x8 bf0 = *(const bf16x8*)(Bws + (size_t)(ch * CH + w * 16 + row16) * MI + quad * 8);
        const bf16x8 bf1 = *(const bf16x8*)(Bws + (size_t)(ch * CH + w * 16 + row16) * MI + 32 + quad * 8);
        const bf16x8 cf0 = *(const bf16x8*)(Cws + (size_t)(w * 16 + row16) * NS + ch * CH + quad * 8);
        const bf16x8 cf1 = *(const bf16x8*)(Cws + (size_t)(w * 16 + row16) * NS + ch * CH + 32 + quad * 8);

        // phase A: Bu chunk -> buDiag (diag-major scatter)
#pragma unroll
        for (int nt = 0; nt < 4; ++nt) {
            floatx4 dacc = {0.f, 0.f, 0.f, 0.f};
            dacc = __builtin_amdgcn_mfma_f32_16x16x32_bf16(bf0, ufr0[nt], dacc, 0, 0, 0);
            dacc = __builtin_amdgcn_mfma_f32_16x16x32_bf16(bf1, ufr1[nt], dacc, 0, 0, 0);
            const int t = nt * 16 + row16;
            const int ibase = w * 16 + quad * 4;
#pragma unroll
            for (int r = 0; r < 4; ++r) {
                const int dd = (ibase + r - t) & 63;
                buDiag[dd * LDD + t] = dacc[r];
            }
        }
        __syncthreads();

        // ---- walk: wave 0; lane d owns row d; streamed float2, no staging
        const int nxt = cur ^ 1;
        if (tid < 64) {
            const int d = tid;
            const int gi = ch * CH + d;
            float run = (gi >= 1) ? Rbuf[rbase + gi - 1] : 0.f;      // chain A seed
            const float carryB = (ch > 0) ? colBuf[cur][d] : 0.f;    // chain B seed
            const int tsplit = 63 - d;
            float exitVal = 0.f;
#pragma unroll 4
            for (int k = 0; k < 32; ++k) {
                const float2 tv = *(const float2*)&buDiag[d * LDD + 2 * k];
                {
                    const int t = 2 * k;
                    run += tv.x;
                    Gb[t * LDU + ((d + t) & 63)] = f2bf(run);
                    const bool sp = (t == tsplit);
                    exitVal = sp ? run : exitVal;
                    run = sp ? carryB : run;
                }
                {
                    const int t = 2 * k + 1;
                    run += tv.y;
                    Gb[t * LDU + ((d + t) & 63)] = f2bf(run);
                    const bool sp = (t == tsplit);
                    exitVal = sp ? run : exitVal;
                    run = sp ? carryB : run;
                }
            }
            if (ch == NCH - 1) fbuf[(size_t)b * SEQ + t0 + tsplit] = exitVal;
            else colBuf[nxt][d] = exitVal;
        }
        __syncthreads();

        // phase B: accY += C[:,chunk] * G[chunk]  (bf16 direct)
#pragma unroll
        for (int nt = 0; nt < 4; ++nt) {
            const int t = nt * 16 + row16;
            bf16x8 g0 = *(const bf16x8*)&Gb[t * LDU + quad * 8];
            bf16x8 g1 = *(const bf16x8*)&Gb[t * LDU + 32 + quad * 8];
            accY[nt] = __builtin_amdgcn_mfma_f32_16x16x32_bf16(cf0, g0, accY[nt], 0, 0, 0);
            accY[nt] = __builtin_amdgcn_mfma_f32_16x16x32_bf16(cf1, g1, accY[nt], 0, 0, 0);
        }
        __syncthreads();
        cur = nxt;
    }

    // epilogue: += D*u, store y
    const bf16x8 df0 = *(const bf16x8*)(Dws + (size_t)(w * 16 + row16) * MI + quad * 8);
    const bf16x8 df1 = *(const bf16x8*)(Dws + (size_t)(w * 16 + row16) * MI + 32 + quad * 8);
#pragma unroll
    for (int nt = 0; nt < 4; ++nt) {
        const int t = nt * 16 + row16;
        accY[nt] = __builtin_amdgcn_mfma_f32_16x16x32_bf16(df0, ufr0[nt], accY[nt], 0, 0, 0);
        accY[nt] = __builtin_amdgcn_mfma_f32_16x16x32_bf16(df1, ufr1[nt], accY[nt], 0, 0, 0);
        const int p0 = w * 16 + quad * 4;
        *(floatx4*)(y + ((size_t)b * SEQ + t0 + t) * PO + p0) = accY[nt];
    }
}

// ---------------------------------------------------------------------------
// s[b][t] = sum_{j=0..t} h[j] f[b][t-j]
// ---------------------------------------------------------------------------
__global__ void __launch_bounds__(256) sconv_kernel(const float* __restrict__ fbuf,
                                                    const float* __restrict__ hbuf,
                                                    float* __restrict__ sbuf) {
    __shared__ float f_l[SEQ];
    __shared__ float h_lc[SEQ + 8];
    __shared__ float part[4][TB];
    const int blk = blockIdx.x, b = blockIdx.y, tid = threadIdx.x;
    const int t0 = blk * TB;
    const int len = t0 + TB;
    {
        const float4* fs = (const float4*)(fbuf + (size_t)b * SEQ);
        const float4* hs = (const float4*)hbuf;
        for (int i = tid; i < len / 4; i += 256) {
            ((float4*)f_l)[i] = fs[i];
            ((float4*)h_lc)[i] = hs[i];
        }
    }
    __syncthreads();
    const int dt = tid & 63, grp = tid >> 6;
    const int t = t0 + dt;
    float acc = 0.f;
    for (int j4 = grp * 4; j4 <= t; j4 += 16) {
        const float4 hv = *(const float4*)&h_lc[j4];
        if (j4 + 0 <= t) acc += hv.x * f_l[t - j4 - 0];
        if (j4 + 1 <= t) acc += hv.y * f_l[t - j4 - 1];
        if (j4 + 2 <= t) acc += hv.z * f_l[t - j4 - 2];
        if (j4 + 3 <= t) acc += hv.w * f_l[t - j4 - 3];
    }
    part[grp][dt] = acc;
    __syncthreads();
    if (tid < TB) {
        sbuf[(size_t)b * SEQ + t0 + tid] =
            part[0][tid] + part[1][tid] + part[2][tid] + part[3][tid];
    }
}

// ---------------------------------------------------------------------------
// corr (MFMA, direct global q-frags, double-buffered Sw, 1 barrier/chunk):
// y[b,t,p] -= sum_j qT[p][j] * s[b, t-1-j]
// ---------------------------------------------------------------------------
__global__ void __launch_bounds__(256) corr_kernel(
    const float* __restrict__ sbuf, const unsigned short* __restrict__ qT,
    float* __restrict__ y) {
    __shared__ float s_l[NS + TB];
    __shared__ unsigned short Sw[2][TB * LDU];
    const int blk = blockIdx.x, b = blockIdx.y, tid = threadIdx.x;
    const int t0 = blk * TB;
    const int lane = tid & 63, w = tid >> 6;
    const int row16 = lane & 15, quad = lane >> 4;
    for (int idx = tid; idx < NS + TB; idx += 256) {
        const int t = t0 - NS + idx;
        s_l[idx] = (t >= 0) ? sbuf[(size_t)b * SEQ + t] : 0.f;
    }
    floatx4 acc[4];
#pragma unroll
    for (int nt = 0; nt < 4; ++nt) acc[nt] = (floatx4){0.f, 0.f, 0.f, 0.f};
    __syncthreads();

    for (int ch = 0; ch < NCH; ++ch) {
        const int buf = ch & 1;
        const bf16x8 qf0 = *(const bf16x8*)(qT + (size_t)(w * 16 + row16) * NS + ch * CH + quad * 8);
        const bf16x8 qf1 = *(const bf16x8*)(qT + (size_t)(w * 16 + row16) * NS + ch * CH + 32 + quad * 8);
        {
            const int r = tid >> 2, c0 = (tid & 3) * 16;
            unsigned short tmp[16];
            const int base = 511 + r - ch * CH - c0;
#pragma unroll
            for (int jj = 0; jj < 16; ++jj) tmp[jj] = f2bf(s_l[base - jj]);
            *(uint4*)&Sw[buf][r * LDU + c0]     = *(uint4*)&tmp[0];
            *(uint4*)&Sw[buf][r * LDU + c0 + 8] = *(uint4*)&tmp[8];
        }
        __syncthreads();
#pragma unroll
        for (int nt = 0; nt < 4; ++nt) {
            const int t = nt * 16 + row16;
            bf16x8 s0 = *(const bf16x8*)&Sw[buf][t * LDU + quad * 8];
            bf16x8 s1 = *(const bf16x8*)&Sw[buf][t * LDU + 32 + quad * 8];
            acc[nt] = __builtin_amdgcn_mfma_f32_16x16x32_bf16(qf0, s0, acc[nt], 0, 0, 0);
            acc[nt] = __builtin_amdgcn_mfma_f32_16x16x32_bf16(qf1, s1, acc[nt], 0, 0, 0);
        }
    }
#pragma unroll
    for (int nt = 0; nt < 4; ++nt) {
        const int t = nt * 16 + row16;
        const int p0 = w * 16 + quad * 4;
        float* yp = y + ((size_t)b * SEQ + t0 + t) * PO + p0;
        floatx4 old = *(const floatx4*)yp;
        *(floatx4*)yp = old - acc[nt];
    }
}

// ---------------------------------------------------------------------------
extern "C" void kernel_launch(void* const* d_in, const int* in_sizes, int n_in,
                              void* d_out, int out_size, void* d_ws,
                              size_t ws_size, hipStream_t stream) {
    const float* u  = (const float*)d_in[0];
    const float* a  = (const float*)d_in[1];
    const float* B  = (const float*)d_in[2];
    const float* Cm = (const float*)d_in[3];
    const float* Dm = (const float*)d_in[4];
    float* y = (float*)d_out;

    char* ws = (char*)d_ws;
    unsigned short* Bws = (unsigned short*)ws;                  ws += NS * MI * 2;
    unsigned short* Cws = (unsigned short*)ws;                  ws += PO * NS * 2;
    unsigned short* Dws = (unsigned short*)ws;                  ws += PO * MI * 2;
    unsigned short* qTw = (unsigned short*)ws;                  ws += PO * NS * 2;
    unsigned short* ubf = (unsigned short*)ws;                  ws += (size_t)NB * SEQ * MI * 2;
    unsigned short* Bft = (unsigned short*)ws;                  ws += (size_t)NS * 4096 * 2;
    float* Sbuf = (float*)ws;                                   ws += (size_t)NB * NTB * NS * 4;
    float* Rbuf = (float*)ws;                                   ws += (size_t)NB * NTB * NS * 4;
    float* fbuf = (float*)ws;                                   ws += (size_t)NB * SEQ * 4;
    float* sbuf = (float*)ws;                                   ws += (size_t)NB * SEQ * 4;
    float* hbuf = (float*)ws;                                   // 2048 floats (~17.5 MB total)

    prep_all_kernel<<<dim3(2896), dim3(256), 0, stream>>>(
        u, B, Cm, Dm, a, ubf, Bft, Bws, Cws, Dws, qTw);
    sgemm_kernel<<<dim3(8, 32), dim3(256), 0, stream>>>(ubf, Bft, Sbuf);
    scan_himp_kernel<<<dim3(NB + 1), dim3(1024), 0, stream>>>(Sbuf, Rbuf, a, hbuf);
    ytile_kernel<<<dim3(NTB, NB), dim3(256), 0, stream>>>(
        ubf, Bws, Cws, Dws, Rbuf, fbuf, y);
    sconv_kernel<<<dim3(NTB, NB), dim3(256), 0, stream>>>(fbuf, hbuf, sbuf);
    corr_kernel<<<dim3(NTB, NB), dim3(256), 0, stream>>>(sbuf, qTw, y);
}